// Round 1
// 270.283 us; speedup vs baseline: 1.0188x; 1.0188x over previous
//
#include <hip/hip_runtime.h>

// B=16, C=64, H=W=192, K=3 (fixed).
// Kernel 1: ker[b,c,i,j] from the tiny MLP (16 blocks, writes 9216 floats to ws).
// Kernel 2: depthwise 3x3. v4: each thread owns ONE quad-column (4 cols) and
// RPT=4 output rows. ALL 6 input-row loads (6 dwordx4 + 12 scalar edges) are
// hoisted ahead of the FMAs -> ~18 independent loads in flight per wave
// (v3's rolling window kept VGPR=32 and only ~2 loads in flight -> latency
// bound at 2.5 TB/s). VGPR target ~56 (<=64 keeps 8 blocks/CU).

#define BB 16
#define CC 64
#define HH 192
#define WW 192
#define KERLEN (CC * 9)     // 576 per batch
#define QW (WW / 4)         // 48 quads per row
#define RPT 4               // output rows per thread
#define TPP (QW * (HH / RPT))   // 48*48 = 2304 tasks per plane
#define BPP (TPP / 256)         // 9 blocks per plane

typedef float f4 __attribute__((ext_vector_type(4)));

// ---- Kernel 1: generate the 1024 per-(b,c) 3x3 kernels into d_ws ----
__global__ __launch_bounds__(256) void gen_kernels(
    const float* __restrict__ d,   // (B, C)
    const float* __restrict__ w1,  // (C, C)
    const float* __restrict__ w2,  // (C*9, C)
    float* __restrict__ ker)       // (B*C*9)
{
    __shared__ float dd[CC];
    __shared__ float hid[CC];
    const int b = blockIdx.x;
    const int t = threadIdx.x;

    if (t < CC) dd[t] = d[b * CC + t];
    __syncthreads();

    if (t < CC) {
        const float* w1r = w1 + t * CC;
        float acc = 0.f;
        #pragma unroll 8
        for (int m = 0; m < CC; ++m) acc += dd[m] * w1r[m];
        hid[t] = acc > 0.f ? acc : 0.1f * acc;
    }
    __syncthreads();

    for (int o = t; o < KERLEN; o += 256) {
        const float* w2r = w2 + o * CC;
        float acc = 0.f;
        #pragma unroll 8
        for (int k = 0; k < CC; ++k) acc += hid[k] * w2r[k];
        ker[b * KERLEN + o] = acc;
    }
}

// ---- Kernel 2: depthwise 3x3, hoisted-load 4-row strip ----
__global__ __launch_bounds__(256, 8) void dconv3x3_v4(
    const float* __restrict__ x,    // (B*C, H, W)
    const float* __restrict__ ker,  // (B*C, 9)
    float* __restrict__ out)        // (B*C, H, W)
{
    const int blk = blockIdx.x;
    const int bc  = blk / BPP;
    const int sub = blk - bc * BPP;

    // block-uniform coefficients -> scalar loads (SGPRs)
    const float* kp = ker + bc * 9;
    const float k00 = kp[0], k01 = kp[1], k02 = kp[2];
    const float k10 = kp[3], k11 = kp[4], k12 = kp[5];
    const float k20 = kp[6], k21 = kp[7], k22 = kp[8];

    const int task = sub * 256 + threadIdx.x;   // 0..2303
    const int rg   = task / QW;                 // row-group 0..47
    const int qw   = task - rg * QW;            // quad col 0..47
    const int w    = qw * 4;
    const int r0   = rg * RPT;

    const bool hasL = (qw > 0);
    const bool hasR = (qw < QW - 1);
    const int  offL = hasL ? -1 : 0;            // safe clamped offsets
    const int  offR = hasR ?  4 : 0;

    const float* __restrict__ xp = x   + (size_t)bc * HH * WW + w;
    float* __restrict__       op = out + (size_t)bc * HH * WW + w;

    f4    c[RPT + 2];
    float l[RPT + 2], r[RPT + 2];
    const f4 zero = {0.f, 0.f, 0.f, 0.f};

    // All 6 row-loads issued before any use: 6x dwordx4 + 12x dword,
    // fully independent -> deep MLP. Indices are compile-time (unrolled),
    // so c[]/l[]/r[] stay in registers (no scratch).
    #pragma unroll
    for (int j = 0; j < RPT + 2; ++j) {
        const int rr  = r0 - 1 + j;
        const int rcl = rr < 0 ? 0 : (rr >= HH ? HH - 1 : rr);
        const float* p = xp + rcl * WW;
        const f4 v     = *(const f4*)p;
        const float lv = p[offL];
        const float rv = p[offR];
        const bool ok  = (rr >= 0) & (rr < HH);
        c[j] = ok ? v : zero;
        l[j] = (ok && hasL) ? lv : 0.f;
        r[j] = (ok && hasR) ? rv : 0.f;
    }

    #pragma unroll
    for (int i = 0; i < RPT; ++i) {
        const f4 ca = c[i], cb = c[i + 1], cd = c[i + 2];
        const float la = l[i], lb = l[i + 1], lc = l[i + 2];
        const float ra = r[i], rb = r[i + 1], rc = r[i + 2];

        f4 o;
        o.x = k00 * la   + k01 * ca.x + k02 * ca.y
            + k10 * lb   + k11 * cb.x + k12 * cb.y
            + k20 * lc   + k21 * cd.x + k22 * cd.y;
        o.y = k00 * ca.x + k01 * ca.y + k02 * ca.z
            + k10 * cb.x + k11 * cb.y + k12 * cb.z
            + k20 * cd.x + k21 * cd.y + k22 * cd.z;
        o.z = k00 * ca.y + k01 * ca.z + k02 * ca.w
            + k10 * cb.y + k11 * cb.z + k12 * cb.w
            + k20 * cd.y + k21 * cd.z + k22 * cd.w;
        o.w = k00 * ca.z + k01 * ca.w + k02 * ra
            + k10 * cb.z + k11 * cb.w + k12 * rb
            + k20 * cd.z + k21 * cd.w + k22 * rc;

        __builtin_nontemporal_store(o, (f4*)(op + (size_t)(r0 + i) * WW));
    }
}

extern "C" void kernel_launch(void* const* d_in, const int* in_sizes, int n_in,
                              void* d_out, int out_size, void* d_ws, size_t ws_size,
                              hipStream_t stream) {
    const float* x0 = (const float*)d_in[0];  // (16,64,192,192)
    const float* d  = (const float*)d_in[1];  // (16,64)
    const float* w1 = (const float*)d_in[2];  // (64,64)
    const float* w2 = (const float*)d_in[3];  // (576,64)
    float* out = (float*)d_out;
    float* ker = (float*)d_ws;                // 9216 floats

    gen_kernels<<<BB, 256, 0, stream>>>(d, w1, w2, ker);
    dconv3x3_v4<<<BB * CC * BPP, 256, 0, stream>>>(x0, ker, out);
}